// Round 1
// baseline (2196.148 us; speedup 1.0000x reference)
//
#include <hip/hip_runtime.h>

// Model: 2-layer LSTM (B=200,T=250,F=14,H=256) + Dense(164,relu) + Dense(8,softmax)
//
// Architecture:
//  - prep:   build padded bf16 x-tensor [T][208][32], zero h0 slabs + flags
//  - lstm1:  52 blocks = 13 batch-groups x 4 hidden-slices. Each block keeps its
//            256 columns of [U1;W1] as MFMA B-fragments in VGPRs (loaded once).
//            Per step: A-frags from seq slab t (bf16), 36 MFMAs, gate math fp32,
//            write h slice to slab t+1, post one-shot flag (agent scope release).
//            Peers spin on flags (agent scope acquire). Slabs are write-once.
//  - lstm2:  same, 8 waves: waves 0-3 compute h2@U2, waves 4-7 compute h1@W2
//            (seq slab t+1), LDS reduction, gates on waves 0-3.
//  - head:   dense+relu+dense+softmax in fp32.
//
// ws usage ~58 MB.

#define T_STEPS 250
#define B_REAL  200
#define BPAD    208
#define FIN     14
#define HID     256
#define NGATE   1024
#define NBG     13      // batch groups of 16 rows
#define HS      4       // hidden-slice blocks per group
#define SLAB    (BPAD*HID)   // 53248 elems per time slab
#define XT_ROW  32
#define XT_ELEMS (T_STEPS*BPAD*XT_ROW)
#define FSTRIDE 32      // u32 per (t,bg) flag record (128B line padding)

typedef __bf16 bf16_t;
typedef __bf16 bf16x8 __attribute__((ext_vector_type(8)));
typedef float  f32x4  __attribute__((ext_vector_type(4)));

__device__ __forceinline__ float sigmoid_f(float x) {
  return 1.f / (1.f + __expf(-x));
}
__device__ __forceinline__ float tanh_f(float x) {
  float e = __expf(2.f * x);
  return 1.f - 2.f / (e + 1.f);
}

// ---------------------------------------------------------------- prep
__global__ void prep_kernel(const float* __restrict__ x,
                            bf16_t* __restrict__ xT,
                            bf16_t* __restrict__ seq,
                            bf16_t* __restrict__ h2seq,
                            unsigned int* __restrict__ flag1,
                            unsigned int* __restrict__ flag2)
{
  const long long F1N = (long long)T_STEPS * NBG * FSTRIDE;
  const long long F2N = (long long)(T_STEPS + 1) * NBG * FSTRIDE;
  long long i = (long long)blockIdx.x * blockDim.x + threadIdx.x;
  const long long total = (long long)XT_ELEMS + SLAB + SLAB + F1N + F2N;
  if (i >= total) return;
  if (i < XT_ELEMS) {
    int t  = (int)(i / (BPAD * XT_ROW));
    int r  = (int)(i % (BPAD * XT_ROW));
    int b  = r / XT_ROW, kk = r % XT_ROW;
    float v = 0.f;
    if (b < B_REAL && kk < FIN) v = x[((long long)b * T_STEPS + t) * FIN + kk];
    xT[i] = (bf16_t)v;
    return;
  }
  i -= XT_ELEMS;
  if (i < SLAB) { seq[i] = (bf16_t)0.f; return; }      // h1_0 = 0
  i -= SLAB;
  if (i < SLAB) { h2seq[i] = (bf16_t)0.f; return; }    // h2_0 = 0
  i -= SLAB;
  if (i < F1N) { flag1[i] = 0u; return; }
  i -= F1N;
  flag2[i] = 0u;
}

// ---------------------------------------------------------------- LSTM layer 1
// grid: 52 blocks x 256 threads (4 waves). wave w owns units [16w,16w+16) of
// this block's 64-unit slice; B-frags (U1 cols for 4 gates, K=256 h + 32 x-pad)
// live in VGPRs for the whole kernel.
__global__ __launch_bounds__(256, 1) void lstm1_kernel(
    const float* __restrict__ W1,   // [14][1024]
    const float* __restrict__ U1,   // [256][1024]
    const float* __restrict__ b1,   // [1024]
    const bf16_t* __restrict__ xT,  // [250][208][32] bf16 (padded)
    bf16_t* __restrict__ seq,       // [251][208][256] bf16, slab0 = zeros
    unsigned int* __restrict__ flag1)
{
  const int bg  = blockIdx.x >> 2;
  const int hsl = blockIdx.x & 3;
  const int b0  = bg * 16;
  const int tid = threadIdx.x;
  const int w   = tid >> 6;
  const int l   = tid & 63;
  const int lr  = l & 15;          // MFMA row (A) / col (B,D)
  const int ag  = l >> 4;          // k-group
  const int ncol = hsl * 64 + w * 16 + lr;   // hidden-unit index 0..255

  // ---- load B fragments once (registers for the whole time loop)
  bf16x8 bfr[4][9];
#pragma unroll
  for (int g = 0; g < 4; ++g) {
    const int n = g * 256 + ncol;
#pragma unroll
    for (int kf = 0; kf < 9; ++kf) {
      bf16x8 v;
#pragma unroll
      for (int e = 0; e < 8; ++e) {
        const int k = kf * 32 + ag * 8 + e;
        float val = 0.f;
        if (k < 256)      val = U1[(long long)k * NGATE + n];
        else if (k < 270) val = W1[(long long)(k - 256) * NGATE + n];
        v[e] = (bf16_t)val;
      }
      bfr[g][kf] = v;
    }
  }
  float bias[4];
#pragma unroll
  for (int g = 0; g < 4; ++g) bias[g] = b1[g * 256 + ncol];
  float cst[4] = {0.f, 0.f, 0.f, 0.f};

  for (int t = 0; t < T_STEPS; ++t) {
    if (t > 0) {
      if (tid < HS) {
        const unsigned int* fp =
            flag1 + ((long long)(t - 1) * NBG + bg) * FSTRIDE + tid;
        while (__hip_atomic_load(fp, __ATOMIC_ACQUIRE,
                                 __HIP_MEMORY_SCOPE_AGENT) == 0u)
          __builtin_amdgcn_s_sleep(1);
      }
      __syncthreads();
    }
    // ---- A fragments: h_t (slab t) + x_t
    const bf16_t* arow = seq + (long long)t * SLAB + (b0 + lr) * HID;
    bf16x8 afr[9];
#pragma unroll
    for (int kf = 0; kf < 8; ++kf)
      afr[kf] = *(const bf16x8*)(arow + kf * 32 + ag * 8);
    afr[8] = *(const bf16x8*)(xT + ((long long)t * BPAD + b0 + lr) * XT_ROW + ag * 8);

    // ---- z = [h,x] @ [U1;W1]
    f32x4 acc[4];
#pragma unroll
    for (int g = 0; g < 4; ++g) {
      f32x4 a = {0.f, 0.f, 0.f, 0.f};
#pragma unroll
      for (int kf = 0; kf < 9; ++kf)
        a = __builtin_amdgcn_mfma_f32_16x16x32_bf16(afr[kf], bfr[g][kf], a, 0, 0, 0);
      acc[g] = a;
    }
    // ---- gates + write h_{t+1} slice
    bf16_t* orow = seq + (long long)(t + 1) * SLAB;
#pragma unroll
    for (int r = 0; r < 4; ++r) {
      const int row = ag * 4 + r;
      const float ig = sigmoid_f(acc[0][r] + bias[0]);
      const float fg = sigmoid_f(acc[1][r] + bias[1]);
      const float gg = tanh_f  (acc[2][r] + bias[2]);
      const float og = sigmoid_f(acc[3][r] + bias[3]);
      const float c  = fg * cst[r] + ig * gg;
      cst[r] = c;
      const float h  = og * tanh_f(c);
      orow[(b0 + row) * HID + ncol] = (bf16_t)h;
    }
    __syncthreads();   // drains this block's stores to its L2
    if (tid == 0)      // release: waitcnt + L2 writeback + flag store
      __hip_atomic_store(flag1 + ((long long)t * NBG + bg) * FSTRIDE + hsl, 1u,
                         __ATOMIC_RELEASE, __HIP_MEMORY_SCOPE_AGENT);
  }
}

// ---------------------------------------------------------------- LSTM layer 2
// grid: 52 blocks x 512 threads (8 waves). waves 0-3 (kh=0): h2@U2 + gates;
// waves 4-7 (kh=1): h1_t@W2 partial, reduced through LDS.
__global__ __launch_bounds__(512, 2) void lstm2_kernel(
    const float* __restrict__ W2,   // [256][1024]
    const float* __restrict__ U2,   // [256][1024]
    const float* __restrict__ b2,   // [1024]
    const bf16_t* __restrict__ seq,    // [251][208][256] (slab t+1 = h1_t)
    bf16_t* __restrict__ h2seq,        // [251][208][256], slab0 = zeros
    unsigned int* __restrict__ flag2)
{
  __shared__ float zs[4096];           // 16 tiles x 16 rows x 16 cols
  const int bg  = blockIdx.x >> 2;
  const int hsl = blockIdx.x & 3;
  const int b0  = bg * 16;
  const int tid = threadIdx.x;
  const int w   = tid >> 6;            // 0..7
  const int l   = tid & 63;
  const int lr  = l & 15;
  const int ag  = l >> 4;
  const int uq  = w & 3;
  const int kh  = w >> 2;              // 0: U2 (h2-half), 1: W2 (h1-half)
  const int ncol = hsl * 64 + uq * 16 + lr;

  const float* Wsrc = kh ? W2 : U2;
  bf16x8 bfr[4][8];
#pragma unroll
  for (int g = 0; g < 4; ++g) {
    const int n = g * 256 + ncol;
#pragma unroll
    for (int kf = 0; kf < 8; ++kf) {
      bf16x8 v;
#pragma unroll
      for (int e = 0; e < 8; ++e)
        v[e] = (bf16_t)Wsrc[(long long)(kf * 32 + ag * 8 + e) * NGATE + n];
      bfr[g][kf] = v;
    }
  }
  float bias[4];
#pragma unroll
  for (int g = 0; g < 4; ++g) bias[g] = b2[g * 256 + ncol];
  float cst[4] = {0.f, 0.f, 0.f, 0.f};

  for (int t = 0; t < T_STEPS; ++t) {
    if (t > 0) {
      if (tid < HS) {
        const unsigned int* fp =
            flag2 + ((long long)t * NBG + bg) * FSTRIDE + tid;
        while (__hip_atomic_load(fp, __ATOMIC_ACQUIRE,
                                 __HIP_MEMORY_SCOPE_AGENT) == 0u)
          __builtin_amdgcn_s_sleep(1);
      }
      __syncthreads();
    }
    const bf16_t* arow = kh
        ? (seq   + (long long)(t + 1) * SLAB + (b0 + lr) * HID)   // h1_t
        : (h2seq + (long long)t       * SLAB + (b0 + lr) * HID);  // h2_t
    bf16x8 afr[8];
#pragma unroll
    for (int kf = 0; kf < 8; ++kf)
      afr[kf] = *(const bf16x8*)(arow + kf * 32 + ag * 8);

    f32x4 acc[4];
#pragma unroll
    for (int g = 0; g < 4; ++g) {
      f32x4 a = {0.f, 0.f, 0.f, 0.f};
#pragma unroll
      for (int kf = 0; kf < 8; ++kf)
        a = __builtin_amdgcn_mfma_f32_16x16x32_bf16(afr[kf], bfr[g][kf], a, 0, 0, 0);
      acc[g] = a;
    }
    if (kh == 1) {
#pragma unroll
      for (int g = 0; g < 4; ++g)
#pragma unroll
        for (int r = 0; r < 4; ++r)
          zs[((g * 4 + uq) * 16 + ag * 4 + r) * 16 + lr] = acc[g][r];
    }
    __syncthreads();
    if (kh == 0) {
      bf16_t* orow = h2seq + (long long)(t + 1) * SLAB;
#pragma unroll
      for (int r = 0; r < 4; ++r) {
        const int row = ag * 4 + r;
        const float zi = acc[0][r] + zs[((0 * 4 + uq) * 16 + row) * 16 + lr] + bias[0];
        const float zf = acc[1][r] + zs[((1 * 4 + uq) * 16 + row) * 16 + lr] + bias[1];
        const float zg = acc[2][r] + zs[((2 * 4 + uq) * 16 + row) * 16 + lr] + bias[2];
        const float zo = acc[3][r] + zs[((3 * 4 + uq) * 16 + row) * 16 + lr] + bias[3];
        const float ig = sigmoid_f(zi);
        const float fg = sigmoid_f(zf);
        const float gg = tanh_f(zg);
        const float og = sigmoid_f(zo);
        const float c  = fg * cst[r] + ig * gg;
        cst[r] = c;
        const float h  = og * tanh_f(c);
        orow[(b0 + row) * HID + ncol] = (bf16_t)h;
      }
    }
    __syncthreads();
    if (tid == 0)
      __hip_atomic_store(flag2 + ((long long)(t + 1) * NBG + bg) * FSTRIDE + hsl,
                         1u, __ATOMIC_RELEASE, __HIP_MEMORY_SCOPE_AGENT);
  }
}

// ---------------------------------------------------------------- head
__global__ __launch_bounds__(64) void head_kernel(
    const bf16_t* __restrict__ h2,   // [208][256] (slab 250)
    const float* __restrict__ Wd,    // [256][164]
    const float* __restrict__ bd,    // [164]
    const float* __restrict__ Ws,    // [164][8]
    const float* __restrict__ bs,    // [8]
    float* __restrict__ out)         // [200][8]
{
  __shared__ float hsm[HID];
  __shared__ float hid[164];
  __shared__ float lg[8];
  const int b = blockIdx.x, tid = threadIdx.x;
  const bf16_t* hr = h2 + (long long)b * HID;
  for (int k = tid; k < HID; k += 64) hsm[k] = (float)hr[k];
  __syncthreads();
  for (int d = tid; d < 164; d += 64) {
    float a = bd[d];
    for (int k = 0; k < HID; ++k) a = fmaf(hsm[k], Wd[k * 164 + d], a);
    hid[d] = fmaxf(a, 0.f);
  }
  __syncthreads();
  if (tid < 8) {
    float a = bs[tid];
    for (int k = 0; k < 164; ++k) a = fmaf(hid[k], Ws[k * 8 + tid], a);
    lg[tid] = a;
  }
  __syncthreads();
  if (tid < 8) {
    float m = lg[0];
#pragma unroll
    for (int j = 1; j < 8; ++j) m = fmaxf(m, lg[j]);
    float s = 0.f;
#pragma unroll
    for (int j = 0; j < 8; ++j) s += __expf(lg[j] - m);
    out[b * 8 + tid] = __expf(lg[tid] - m) / s;
  }
}

// ---------------------------------------------------------------- launch
extern "C" void kernel_launch(void* const* d_in, const int* in_sizes, int n_in,
                              void* d_out, int out_size, void* d_ws, size_t ws_size,
                              hipStream_t stream)
{
  const float* x  = (const float*)d_in[0];
  const float* W1 = (const float*)d_in[1];
  const float* U1 = (const float*)d_in[2];
  const float* b1 = (const float*)d_in[3];
  const float* W2 = (const float*)d_in[4];
  const float* U2 = (const float*)d_in[5];
  const float* b2 = (const float*)d_in[6];
  const float* Wd = (const float*)d_in[7];
  const float* bd = (const float*)d_in[8];
  const float* Ws = (const float*)d_in[9];
  const float* bs = (const float*)d_in[10];
  (void)in_sizes; (void)n_in; (void)out_size; (void)ws_size;

  char* p = (char*)d_ws;
  size_t off = 0;
  auto carve = [&](size_t bytes) -> void* {
    void* r = p + off;
    off = (off + bytes + 255) & ~(size_t)255;
    return r;
  };
  bf16_t* xT    = (bf16_t*)carve((size_t)XT_ELEMS * 2);
  bf16_t* seq   = (bf16_t*)carve((size_t)(T_STEPS + 1) * SLAB * 2);
  bf16_t* h2s   = (bf16_t*)carve((size_t)(T_STEPS + 1) * SLAB * 2);
  unsigned int* flag1 = (unsigned int*)carve((size_t)T_STEPS * NBG * FSTRIDE * 4);
  unsigned int* flag2 = (unsigned int*)carve((size_t)(T_STEPS + 1) * NBG * FSTRIDE * 4);

  const long long prep_total = (long long)XT_ELEMS + SLAB + SLAB +
                               (long long)T_STEPS * NBG * FSTRIDE +
                               (long long)(T_STEPS + 1) * NBG * FSTRIDE;
  const int pb = (int)((prep_total + 255) / 256);

  prep_kernel<<<pb, 256, 0, stream>>>(x, xT, seq, h2s, flag1, flag2);
  lstm1_kernel<<<NBG * HS, 256, 0, stream>>>(W1, U1, b1, xT, seq, flag1);
  lstm2_kernel<<<NBG * HS, 512, 0, stream>>>(W2, U2, b2, seq, h2s, flag2);
  head_kernel<<<B_REAL, 64, 0, stream>>>(h2s + (long long)T_STEPS * SLAB,
                                         Wd, bd, Ws, bs, (float*)d_out);
}

// Round 2
// 2082.563 us; speedup vs baseline: 1.0545x; 1.0545x over previous
//
#include <hip/hip_runtime.h>

// 2-layer LSTM (B=200,T=250,F=14,H=256) + Dense(164,relu) + Dense(8,softmax)
//
// v2: fused lstm1+lstm2 (layer2 skewed 1 step), relaxed-poll + single acquire
//     fence per step, asm keep-alive to force weight VGPR residency.
//
//  - blocks [0,26):   layer1. bg = blk>>1, hsl = blk&1 (128 hidden units each).
//                     8 waves x 16 units; each wave holds 4 gate-tiles x 9 kfrags
//                     of [U1;W1] in VGPRs (144 VGPRs), kept alive via asm.
//  - blocks [26,78):  layer2. bg = (blk-26)>>2, hsl = &3 (64 units). 8 waves =
//                     4 col-quarters x 2 K-halves (U2 | W2), LDS z-reduction.
//  - sync: write-once slabs seq/h2s per t; one-shot flags; producers release
//          (agent) once per step; consumers poll with RELAXED agent loads
//          (sc1, no L2 invalidate) + one acquire fence after flags observed.

#define T_STEPS 250
#define B_REAL  200
#define BPAD    208
#define FIN     14
#define HID     256
#define NGATE   1024
#define NBG     13
#define L1S     2
#define L2S     4
#define L1BLK   (NBG*L1S)    // 26
#define L2BLK   (NBG*L2S)    // 52
#define SLAB    (BPAD*HID)
#define XT_ROW  32
#define XT_ELEMS (T_STEPS*BPAD*XT_ROW)
#define FSTRIDE 32

typedef __bf16 bf16_t;
typedef __bf16 bf16x8 __attribute__((ext_vector_type(8)));
typedef float  f32x4  __attribute__((ext_vector_type(4)));

__device__ __forceinline__ float sigmoid_f(float x) {
  return 1.f / (1.f + __expf(-x));
}
__device__ __forceinline__ float tanh_f(float x) {
  float e = __expf(2.f * x);
  return 1.f - 2.f / (e + 1.f);
}

// relaxed agent poll (sc1 load, bypasses stale L2) with periodic acquire
// fallback as insurance against any cached-poll pathology.
__device__ __forceinline__ void poll_flag(const unsigned int* fp) {
  unsigned int v = __hip_atomic_load(fp, __ATOMIC_RELAXED, __HIP_MEMORY_SCOPE_AGENT);
  int spins = 0;
  while (v == 0u) {
    __builtin_amdgcn_s_sleep(1);
    if ((++spins & 255) == 0)
      v = __hip_atomic_load(fp, __ATOMIC_ACQUIRE, __HIP_MEMORY_SCOPE_AGENT);
    else
      v = __hip_atomic_load(fp, __ATOMIC_RELAXED, __HIP_MEMORY_SCOPE_AGENT);
  }
}

// ---------------------------------------------------------------- prep
__global__ void prep_kernel(const float* __restrict__ x,
                            bf16_t* __restrict__ xT,
                            bf16_t* __restrict__ seq,
                            bf16_t* __restrict__ h2seq,
                            unsigned int* __restrict__ flag1,
                            unsigned int* __restrict__ flag2)
{
  const long long F1N = (long long)T_STEPS * NBG * FSTRIDE;
  const long long F2N = (long long)(T_STEPS + 1) * NBG * FSTRIDE;
  long long i = (long long)blockIdx.x * blockDim.x + threadIdx.x;
  const long long total = (long long)XT_ELEMS + SLAB + SLAB + F1N + F2N;
  if (i >= total) return;
  if (i < XT_ELEMS) {
    int t  = (int)(i / (BPAD * XT_ROW));
    int r  = (int)(i % (BPAD * XT_ROW));
    int b  = r / XT_ROW, kk = r % XT_ROW;
    float v = 0.f;
    if (b < B_REAL && kk < FIN) v = x[((long long)b * T_STEPS + t) * FIN + kk];
    xT[i] = (bf16_t)v;
    return;
  }
  i -= XT_ELEMS;
  if (i < SLAB) { seq[i] = (bf16_t)0.f; return; }
  i -= SLAB;
  if (i < SLAB) { h2seq[i] = (bf16_t)0.f; return; }
  i -= SLAB;
  if (i < F1N) { flag1[i] = 0u; return; }
  i -= F1N;
  flag2[i] = 0u;
}

// ---------------------------------------------------------------- fused LSTM
__global__ __launch_bounds__(512, 2) void lstm_fused(
    const float* __restrict__ W1, const float* __restrict__ U1,
    const float* __restrict__ b1,
    const float* __restrict__ W2, const float* __restrict__ U2,
    const float* __restrict__ b2,
    const bf16_t* __restrict__ xT,
    bf16_t* __restrict__ seq, bf16_t* __restrict__ h2s,
    unsigned int* __restrict__ flag1, unsigned int* __restrict__ flag2)
{
  __shared__ float zs[4096];
  const int tid = threadIdx.x;
  const int l   = tid & 63;
  const int lr  = l & 15;
  const int ag  = l >> 4;
  const int w   = tid >> 6;

  if (blockIdx.x < L1BLK) {
    // ================= layer 1 =================
    const int bg   = blockIdx.x >> 1;
    const int hsl  = blockIdx.x & 1;
    const int b0   = bg * 16;
    const int unit = hsl * 128 + w * 16 + lr;

    f32x4 wb[4][9];
#pragma unroll
    for (int g = 0; g < 4; ++g) {
      const int n = g * 256 + unit;
#pragma unroll
      for (int kf = 0; kf < 9; ++kf) {
        bf16x8 v;
#pragma unroll
        for (int e = 0; e < 8; ++e) {
          const int k = kf * 32 + ag * 8 + e;
          float val = 0.f;
          if (k < 256)            val = U1[(long long)k * NGATE + n];
          else if (k - 256 < FIN) val = W1[(long long)(k - 256) * NGATE + n];
          v[e] = (bf16_t)val;
        }
        wb[g][kf] = __builtin_bit_cast(f32x4, v);
      }
    }
    float bias[4];
#pragma unroll
    for (int g = 0; g < 4; ++g) bias[g] = b1[g * 256 + unit];
    float cst[4] = {0.f, 0.f, 0.f, 0.f};

    for (int t = 0; t < T_STEPS; ++t) {
      if (t > 0) {
        if (tid < L1S)
          poll_flag(flag1 + ((long long)(t - 1) * NBG + bg) * FSTRIDE + tid);
        __syncthreads();
        __builtin_amdgcn_fence(__ATOMIC_ACQUIRE, "agent");
      }
      // keep weights pinned in VGPRs (opaque per-iteration use+def)
#pragma unroll
      for (int g = 0; g < 4; ++g)
#pragma unroll
        for (int kf = 0; kf < 9; ++kf)
          asm volatile("" : "+v"(wb[g][kf]));

      const bf16_t* arow = seq + (long long)t * SLAB + (b0 + lr) * HID;
      f32x4 acc[4] = {{0.f,0.f,0.f,0.f},{0.f,0.f,0.f,0.f},
                      {0.f,0.f,0.f,0.f},{0.f,0.f,0.f,0.f}};
#pragma unroll
      for (int kf = 0; kf < 8; ++kf) {
        const bf16x8 a = *(const bf16x8*)(arow + kf * 32 + ag * 8);
#pragma unroll
        for (int g = 0; g < 4; ++g)
          acc[g] = __builtin_amdgcn_mfma_f32_16x16x32_bf16(
              a, __builtin_bit_cast(bf16x8, wb[g][kf]), acc[g], 0, 0, 0);
      }
      {
        const bf16x8 ax = *(const bf16x8*)(xT + ((long long)t * BPAD + b0 + lr) * XT_ROW + ag * 8);
#pragma unroll
        for (int g = 0; g < 4; ++g)
          acc[g] = __builtin_amdgcn_mfma_f32_16x16x32_bf16(
              ax, __builtin_bit_cast(bf16x8, wb[g][8]), acc[g], 0, 0, 0);
      }
      bf16_t* orow = seq + (long long)(t + 1) * SLAB;
#pragma unroll
      for (int r = 0; r < 4; ++r) {
        const int row = ag * 4 + r;
        const float ig = sigmoid_f(acc[0][r] + bias[0]);
        const float fg = sigmoid_f(acc[1][r] + bias[1]);
        const float gg = tanh_f  (acc[2][r] + bias[2]);
        const float og = sigmoid_f(acc[3][r] + bias[3]);
        const float c  = fg * cst[r] + ig * gg;
        cst[r] = c;
        orow[(b0 + row) * HID + unit] = (bf16_t)(og * tanh_f(c));
      }
      __syncthreads();   // all waves' stores acked in L2
      if (tid == 0)      // release: waitcnt + wbl2 + flag store (agent)
        __hip_atomic_store(flag1 + ((long long)t * NBG + bg) * FSTRIDE + hsl,
                           1u, __ATOMIC_RELEASE, __HIP_MEMORY_SCOPE_AGENT);
    }
  } else {
    // ================= layer 2 =================
    const int idx  = blockIdx.x - L1BLK;
    const int bg   = idx >> 2;
    const int hsl  = idx & 3;
    const int b0   = bg * 16;
    const int uq   = w & 3;
    const int kh   = w >> 2;          // 0: U2 (h2 half), 1: W2 (h1 half)
    const int unit = hsl * 64 + uq * 16 + lr;

    const float* Wsrc = kh ? W2 : U2;
    f32x4 wb[4][8];
#pragma unroll
    for (int g = 0; g < 4; ++g) {
      const int n = g * 256 + unit;
#pragma unroll
      for (int kf = 0; kf < 8; ++kf) {
        bf16x8 v;
#pragma unroll
        for (int e = 0; e < 8; ++e)
          v[e] = (bf16_t)Wsrc[(long long)(kf * 32 + ag * 8 + e) * NGATE + n];
        wb[g][kf] = __builtin_bit_cast(f32x4, v);
      }
    }
    float bias[4];
#pragma unroll
    for (int g = 0; g < 4; ++g) bias[g] = b2[g * 256 + unit];
    float cst[4] = {0.f, 0.f, 0.f, 0.f};

    for (int t = 0; t < T_STEPS; ++t) {
      if (tid < L1S)                       // h1_t ready?
        poll_flag(flag1 + ((long long)t * NBG + bg) * FSTRIDE + tid);
      if (t > 0 && tid >= 2 && tid < 2 + L2S)  // h2_{t-1} ready?
        poll_flag(flag2 + ((long long)t * NBG + bg) * FSTRIDE + (tid - 2));
      __syncthreads();
      __builtin_amdgcn_fence(__ATOMIC_ACQUIRE, "agent");

#pragma unroll
      for (int g = 0; g < 4; ++g)
#pragma unroll
        for (int kf = 0; kf < 8; ++kf)
          asm volatile("" : "+v"(wb[g][kf]));

      const bf16_t* arow = kh
          ? (seq + (long long)(t + 1) * SLAB + (b0 + lr) * HID)   // h1_t
          : (h2s + (long long)t       * SLAB + (b0 + lr) * HID);  // h2_t
      f32x4 acc[4] = {{0.f,0.f,0.f,0.f},{0.f,0.f,0.f,0.f},
                      {0.f,0.f,0.f,0.f},{0.f,0.f,0.f,0.f}};
#pragma unroll
      for (int kf = 0; kf < 8; ++kf) {
        const bf16x8 a = *(const bf16x8*)(arow + kf * 32 + ag * 8);
#pragma unroll
        for (int g = 0; g < 4; ++g)
          acc[g] = __builtin_amdgcn_mfma_f32_16x16x32_bf16(
              a, __builtin_bit_cast(bf16x8, wb[g][kf]), acc[g], 0, 0, 0);
      }
      if (kh == 1) {
#pragma unroll
        for (int g = 0; g < 4; ++g)
#pragma unroll
          for (int r = 0; r < 4; ++r)
            zs[((g * 4 + uq) * 16 + ag * 4 + r) * 16 + lr] = acc[g][r];
      }
      __syncthreads();
      if (kh == 0) {
        bf16_t* orow = h2s + (long long)(t + 1) * SLAB;
#pragma unroll
        for (int r = 0; r < 4; ++r) {
          const int row = ag * 4 + r;
          const float zi = acc[0][r] + zs[((0 * 4 + uq) * 16 + row) * 16 + lr] + bias[0];
          const float zf = acc[1][r] + zs[((1 * 4 + uq) * 16 + row) * 16 + lr] + bias[1];
          const float zg = acc[2][r] + zs[((2 * 4 + uq) * 16 + row) * 16 + lr] + bias[2];
          const float zo = acc[3][r] + zs[((3 * 4 + uq) * 16 + row) * 16 + lr] + bias[3];
          const float ig = sigmoid_f(zi);
          const float fg = sigmoid_f(zf);
          const float gg = tanh_f(zg);
          const float og = sigmoid_f(zo);
          const float c  = fg * cst[r] + ig * gg;
          cst[r] = c;
          orow[(b0 + row) * HID + unit] = (bf16_t)(og * tanh_f(c));
        }
      }
      __syncthreads();
      if (tid == 0)
        __hip_atomic_store(flag2 + ((long long)(t + 1) * NBG + bg) * FSTRIDE + hsl,
                           1u, __ATOMIC_RELEASE, __HIP_MEMORY_SCOPE_AGENT);
    }
  }
}

// ---------------------------------------------------------------- head
__global__ __launch_bounds__(64) void head_kernel(
    const bf16_t* __restrict__ h2,
    const float* __restrict__ Wd, const float* __restrict__ bd,
    const float* __restrict__ Ws, const float* __restrict__ bs,
    float* __restrict__ out)
{
  __shared__ float hsm[HID];
  __shared__ float hid[164];
  __shared__ float lg[8];
  const int b = blockIdx.x, tid = threadIdx.x;
  const bf16_t* hr = h2 + (long long)b * HID;
  for (int k = tid; k < HID; k += 64) hsm[k] = (float)hr[k];
  __syncthreads();
  for (int d = tid; d < 164; d += 64) {
    float a = bd[d];
    for (int k = 0; k < HID; ++k) a = fmaf(hsm[k], Wd[k * 164 + d], a);
    hid[d] = fmaxf(a, 0.f);
  }
  __syncthreads();
  if (tid < 8) {
    float a = bs[tid];
    for (int k = 0; k < 164; ++k) a = fmaf(hid[k], Ws[k * 8 + tid], a);
    lg[tid] = a;
  }
  __syncthreads();
  if (tid < 8) {
    float m = lg[0];
#pragma unroll
    for (int j = 1; j < 8; ++j) m = fmaxf(m, lg[j]);
    float s = 0.f;
#pragma unroll
    for (int j = 0; j < 8; ++j) s += __expf(lg[j] - m);
    out[b * 8 + tid] = __expf(lg[tid] - m) / s;
  }
}

// ---------------------------------------------------------------- launch
extern "C" void kernel_launch(void* const* d_in, const int* in_sizes, int n_in,
                              void* d_out, int out_size, void* d_ws, size_t ws_size,
                              hipStream_t stream)
{
  const float* x  = (const float*)d_in[0];
  const float* W1 = (const float*)d_in[1];
  const float* U1 = (const float*)d_in[2];
  const float* b1 = (const float*)d_in[3];
  const float* W2 = (const float*)d_in[4];
  const float* U2 = (const float*)d_in[5];
  const float* b2 = (const float*)d_in[6];
  const float* Wd = (const float*)d_in[7];
  const float* bd = (const float*)d_in[8];
  const float* Ws = (const float*)d_in[9];
  const float* bs = (const float*)d_in[10];
  (void)in_sizes; (void)n_in; (void)out_size; (void)ws_size;

  char* p = (char*)d_ws;
  size_t off = 0;
  auto carve = [&](size_t bytes) -> void* {
    void* r = p + off;
    off = (off + bytes + 255) & ~(size_t)255;
    return r;
  };
  bf16_t* xT  = (bf16_t*)carve((size_t)XT_ELEMS * 2);
  bf16_t* seq = (bf16_t*)carve((size_t)(T_STEPS + 1) * SLAB * 2);
  bf16_t* h2s = (bf16_t*)carve((size_t)(T_STEPS + 1) * SLAB * 2);
  unsigned int* flag1 = (unsigned int*)carve((size_t)T_STEPS * NBG * FSTRIDE * 4);
  unsigned int* flag2 = (unsigned int*)carve((size_t)(T_STEPS + 1) * NBG * FSTRIDE * 4);

  const long long prep_total = (long long)XT_ELEMS + SLAB + SLAB +
                               (long long)T_STEPS * NBG * FSTRIDE +
                               (long long)(T_STEPS + 1) * NBG * FSTRIDE;
  const int pb = (int)((prep_total + 255) / 256);

  prep_kernel<<<pb, 256, 0, stream>>>(x, xT, seq, h2s, flag1, flag2);
  lstm_fused<<<L1BLK + L2BLK, 512, 0, stream>>>(W1, U1, b1, W2, U2, b2,
                                                xT, seq, h2s, flag1, flag2);
  head_kernel<<<B_REAL, 64, 0, stream>>>(h2s + (long long)T_STEPS * SLAB,
                                         Wd, bd, Ws, bs, (float*)d_out);
}

// Round 3
// 1252.334 us; speedup vs baseline: 1.7536x; 1.6629x over previous
//
#include <hip/hip_runtime.h>

// 2-layer LSTM (B=200,T=250,F=14,H=256) + Dense(164,relu) + Dense(8,softmax)
//
// v3: XCD-clustered groups + cheap same-L2 sync protocol.
//
// Geometry: 13 batch-groups x 6 roles (2 layer1 hidden-slices + 4 layer2
// hidden-slices). All sync edges are within a group. Blocks of group g are
// placed at blockIdx === g (mod 8) so round-robin dispatch puts the whole
// group on ONE XCD (shared L2).
//
// Sync protocol (hang-proof even if the XCD mapping assumption fails):
//  producer step t:  plain h stores (write-through -> shared L2)
//                    -> vmcnt(0) + barrier -> flagA[t] store sc0 (L2)
//                    -> mirror h stores sc0+sc1 (same addresses, -> fabric/MALL)
//    step t+1 top:   vmcnt(0) + barrier (mirrors drained) -> flagB[t] store sc1
//                    (posted BEFORE polling t+1 flags -> no circular wait)
//  consumer: poll flagA with sc0 loads (fast, same-L2); every 8th poll also
//            check flagB with sc1 (fabric). flagA fired -> plain loads hit the
//            shared L2. flagB-only fired (cross-XCD) -> one agent acquire
//            fence, then plain loads fetch from MALL (mirror-written).
//  Safety: slabs/flags are write-once per t; flags are monotonic 0->1, so any
//  stale cached value is 0 (just a delayed poll, never a false ready).

#define T_STEPS 250
#define B_REAL  200
#define BPAD    208
#define FIN     14
#define HID     256
#define NGATE   1024
#define NBG     13
#define L1S     2
#define L2S     4
#define SLAB    (BPAD*HID)
#define XT_ROW  32
#define XT_ELEMS (T_STEPS*BPAD*XT_ROW)
#define FSTRIDE 32
#define F1N     ((long long)T_STEPS*NBG*FSTRIDE)
#define F2N     ((long long)(T_STEPS+1)*NBG*FSTRIDE)

typedef __bf16 bf16_t;
typedef __bf16 bf16x8 __attribute__((ext_vector_type(8)));
typedef float  f32x4  __attribute__((ext_vector_type(4)));

__device__ __forceinline__ float sigmoid_f(float x) {
  return 1.f / (1.f + __expf(-x));
}
__device__ __forceinline__ float tanh_f(float x) {
  float e = __expf(2.f * x);
  return 1.f - 2.f / (e + 1.f);
}

// ---- cache-scoped flag ops (see protocol comment) ----
__device__ __forceinline__ unsigned int ld_flag_sc0(const unsigned int* p) {
  unsigned int v;
  asm volatile("global_load_dword %0, %1, off sc0\n\ts_waitcnt vmcnt(0)"
               : "=v"(v) : "v"(p) : "memory");
  return v;
}
__device__ __forceinline__ unsigned int ld_flag_sc01(const unsigned int* p) {
  unsigned int v;
  asm volatile("global_load_dword %0, %1, off sc0 sc1\n\ts_waitcnt vmcnt(0)"
               : "=v"(v) : "v"(p) : "memory");
  return v;
}
__device__ __forceinline__ void st_flag_sc0(unsigned int* p) {
  unsigned int one = 1u;
  asm volatile("global_store_dword %0, %1, off sc0" :: "v"(p), "v"(one) : "memory");
}
__device__ __forceinline__ void st_flag_sc01(unsigned int* p) {
  unsigned int one = 1u;
  asm volatile("global_store_dword %0, %1, off sc0 sc1" :: "v"(p), "v"(one) : "memory");
}
__device__ __forceinline__ void st_bf16_sc01(bf16_t* p, bf16_t v) {
  unsigned int u = (unsigned int)__builtin_bit_cast(unsigned short, v);
  asm volatile("global_store_short %0, %1, off sc0 sc1" :: "v"(p), "v"(u) : "memory");
}
__device__ __forceinline__ void waitcnt0() {
  asm volatile("s_waitcnt vmcnt(0)" ::: "memory");
}

// returns 0 if observed via flagA (same-L2 fast path), 1 if via flagB (fabric)
__device__ __forceinline__ int poll_dual(const unsigned int* fa,
                                         const unsigned int* fb) {
  int it = 0;
  for (;;) {
    if (ld_flag_sc0(fa) != 0u) return 0;
    if ((it & 7) == 7 && ld_flag_sc01(fb) != 0u) return 1;
    __builtin_amdgcn_s_sleep(1);
    ++it;
  }
}

__device__ __forceinline__ long long fidx(int t, int g, int s) {
  return ((long long)t * NBG + g) * FSTRIDE + s;
}

// ---------------------------------------------------------------- prep
__global__ void prep_kernel(const float* __restrict__ x,
                            bf16_t* __restrict__ xT,
                            bf16_t* __restrict__ seq,
                            bf16_t* __restrict__ h2seq,
                            unsigned int* __restrict__ fa1,
                            unsigned int* __restrict__ fb1,
                            unsigned int* __restrict__ fa2,
                            unsigned int* __restrict__ fb2)
{
  long long i = (long long)blockIdx.x * blockDim.x + threadIdx.x;
  const long long total = (long long)XT_ELEMS + SLAB + SLAB + 2*F1N + 2*F2N;
  if (i >= total) return;
  if (i < XT_ELEMS) {
    int t  = (int)(i / (BPAD * XT_ROW));
    int r  = (int)(i % (BPAD * XT_ROW));
    int b  = r / XT_ROW, kk = r % XT_ROW;
    float v = 0.f;
    if (b < B_REAL && kk < FIN) v = x[((long long)b * T_STEPS + t) * FIN + kk];
    xT[i] = (bf16_t)v;
    return;
  }
  i -= XT_ELEMS;
  if (i < SLAB) { seq[i] = (bf16_t)0.f; return; }
  i -= SLAB;
  if (i < SLAB) { h2seq[i] = (bf16_t)0.f; return; }
  i -= SLAB;
  if (i < F1N) { fa1[i] = 0u; return; }
  i -= F1N;
  if (i < F1N) { fb1[i] = 0u; return; }
  i -= F1N;
  if (i < F2N) { fa2[i] = 0u; return; }
  i -= F2N;
  fb2[i] = 0u;
}

// ---------------------------------------------------------------- fused LSTM
__global__ __launch_bounds__(512, 2) void lstm_fused(
    const float* __restrict__ W1, const float* __restrict__ U1,
    const float* __restrict__ b1,
    const float* __restrict__ W2, const float* __restrict__ U2,
    const float* __restrict__ b2,
    const bf16_t* __restrict__ xT,
    bf16_t* __restrict__ seq, bf16_t* __restrict__ h2s,
    unsigned int* __restrict__ fa1, unsigned int* __restrict__ fb1,
    unsigned int* __restrict__ fa2, unsigned int* __restrict__ fb2)
{
  __shared__ float zs[4096];
  // ---- XCD-clustered decode: group g lives at blockIdx === g (mod 8)
  const int xcd = blockIdx.x & 7;
  const int slot = blockIdx.x >> 3;          // 0..11
  int g, role;
  if (slot < 6)      { g = xcd;     role = slot; }
  else if (xcd < 5)  { g = 8 + xcd; role = slot - 6; }
  else return;                               // idle pad block

  const int tid = threadIdx.x;
  const int l   = tid & 63;
  const int lr  = l & 15;
  const int ag  = l >> 4;
  const int w   = tid >> 6;
  const int b0  = g * 16;

  if (role < L1S) {
    // ================= layer 1 =================
    const int hsl  = role;
    const int unit = hsl * 128 + w * 16 + lr;

    f32x4 wb[4][9];
#pragma unroll
    for (int gg = 0; gg < 4; ++gg) {
      const int n = gg * 256 + unit;
#pragma unroll
      for (int kf = 0; kf < 9; ++kf) {
        bf16x8 v;
#pragma unroll
        for (int e = 0; e < 8; ++e) {
          const int k = kf * 32 + ag * 8 + e;
          float val = 0.f;
          if (k < 256)            val = U1[(long long)k * NGATE + n];
          else if (k - 256 < FIN) val = W1[(long long)(k - 256) * NGATE + n];
          v[e] = (bf16_t)val;
        }
        wb[gg][kf] = __builtin_bit_cast(f32x4, v);
      }
    }
    float bias[4];
#pragma unroll
    for (int gg = 0; gg < 4; ++gg) bias[gg] = b1[gg * 256 + unit];
    float cst[4] = {0.f, 0.f, 0.f, 0.f};

    for (int t = 0; t < T_STEPS; ++t) {
      if (t > 0) {
        // drain last step's mirror stores, then publish flagB(t-1) BEFORE
        // polling (no circular wait), then poll peers' t-1 flags per-wave.
        waitcnt0();
        __syncthreads();
        if (tid == 0) st_flag_sc01(fb1 + fidx(t - 1, g, hsl));
        int slow = 0;
        if (l < L1S)
          slow = poll_dual(fa1 + fidx(t - 1, g, l), fb1 + fidx(t - 1, g, l));
        if (__any(slow))
          __builtin_amdgcn_fence(__ATOMIC_ACQUIRE, "agent");
      }
#pragma unroll
      for (int gg = 0; gg < 4; ++gg)
#pragma unroll
        for (int kf = 0; kf < 9; ++kf)
          asm volatile("" : "+v"(wb[gg][kf]));

      const bf16_t* arow = seq + (long long)t * SLAB + (b0 + lr) * HID;
      f32x4 acc[4] = {{0.f,0.f,0.f,0.f},{0.f,0.f,0.f,0.f},
                      {0.f,0.f,0.f,0.f},{0.f,0.f,0.f,0.f}};
#pragma unroll
      for (int kf = 0; kf < 8; ++kf) {
        const bf16x8 a = *(const bf16x8*)(arow + kf * 32 + ag * 8);
#pragma unroll
        for (int gg = 0; gg < 4; ++gg)
          acc[gg] = __builtin_amdgcn_mfma_f32_16x16x32_bf16(
              a, __builtin_bit_cast(bf16x8, wb[gg][kf]), acc[gg], 0, 0, 0);
      }
      {
        const bf16x8 ax = *(const bf16x8*)(xT + ((long long)t * BPAD + b0 + lr) * XT_ROW + ag * 8);
#pragma unroll
        for (int gg = 0; gg < 4; ++gg)
          acc[gg] = __builtin_amdgcn_mfma_f32_16x16x32_bf16(
              ax, __builtin_bit_cast(bf16x8, wb[gg][8]), acc[gg], 0, 0, 0);
      }
      bf16_t* orow = seq + (long long)(t + 1) * SLAB;
      bf16_t hv[4];
#pragma unroll
      for (int r = 0; r < 4; ++r) {
        const float ig = sigmoid_f(acc[0][r] + bias[0]);
        const float fg = sigmoid_f(acc[1][r] + bias[1]);
        const float gg = tanh_f  (acc[2][r] + bias[2]);
        const float og = sigmoid_f(acc[3][r] + bias[3]);
        const float c  = fg * cst[r] + ig * gg;
        cst[r] = c;
        hv[r] = (bf16_t)(og * tanh_f(c));
        orow[(b0 + ag * 4 + r) * HID + unit] = hv[r];     // plain (-> L2)
      }
      waitcnt0();
      __syncthreads();                                     // stores in L2
      if (tid == 0) st_flag_sc0(fa1 + fidx(t, g, hsl));    // fast flag
#pragma unroll
      for (int r = 0; r < 4; ++r)                          // fabric mirror
        st_bf16_sc01(orow + (b0 + ag * 4 + r) * HID + unit, hv[r]);
    }
    waitcnt0();
    __syncthreads();
    if (tid == 0) st_flag_sc01(fb1 + fidx(T_STEPS - 1, g, hsl));
  } else {
    // ================= layer 2 =================
    const int hsl  = role - L1S;
    const int uq   = w & 3;
    const int kh   = w >> 2;          // 0: U2 (h2 half) + gates; 1: W2 (h1 half)
    const int unit = hsl * 64 + uq * 16 + lr;

    const float* Wsrc = kh ? W2 : U2;
    f32x4 wb[4][8];
#pragma unroll
    for (int gg = 0; gg < 4; ++gg) {
      const int n = gg * 256 + unit;
#pragma unroll
      for (int kf = 0; kf < 8; ++kf) {
        bf16x8 v;
#pragma unroll
        for (int e = 0; e < 8; ++e)
          v[e] = (bf16_t)Wsrc[(long long)(kf * 32 + ag * 8 + e) * NGATE + n];
        wb[gg][kf] = __builtin_bit_cast(f32x4, v);
      }
    }
    float bias[4];
#pragma unroll
    for (int gg = 0; gg < 4; ++gg) bias[gg] = b2[gg * 256 + unit];
    float cst[4] = {0.f, 0.f, 0.f, 0.f};

    for (int t = 0; t < T_STEPS; ++t) {
      waitcnt0();
      __syncthreads();
      if (t > 0 && tid == 0) st_flag_sc01(fb2 + fidx(t, g, hsl));
      int slow = 0;
      if (kh == 1) {                      // needs h1_t (flag1[t])
        if (l < L1S)
          slow = poll_dual(fa1 + fidx(t, g, l), fb1 + fidx(t, g, l));
      } else if (t > 0) {                 // needs h2_{t-1} (flag2[t])
        if (l < L2S)
          slow = poll_dual(fa2 + fidx(t, g, l), fb2 + fidx(t, g, l));
      }
      if (__any(slow))
        __builtin_amdgcn_fence(__ATOMIC_ACQUIRE, "agent");
#pragma unroll
      for (int gg = 0; gg < 4; ++gg)
#pragma unroll
        for (int kf = 0; kf < 8; ++kf)
          asm volatile("" : "+v"(wb[gg][kf]));

      const bf16_t* arow = kh
          ? (seq + (long long)(t + 1) * SLAB + (b0 + lr) * HID)   // h1_t
          : (h2s + (long long)t       * SLAB + (b0 + lr) * HID);  // h2_t
      f32x4 acc[4] = {{0.f,0.f,0.f,0.f},{0.f,0.f,0.f,0.f},
                      {0.f,0.f,0.f,0.f},{0.f,0.f,0.f,0.f}};
#pragma unroll
      for (int kf = 0; kf < 8; ++kf) {
        const bf16x8 a = *(const bf16x8*)(arow + kf * 32 + ag * 8);
#pragma unroll
        for (int gg = 0; gg < 4; ++gg)
          acc[gg] = __builtin_amdgcn_mfma_f32_16x16x32_bf16(
              a, __builtin_bit_cast(bf16x8, wb[gg][kf]), acc[gg], 0, 0, 0);
      }
      if (kh == 1) {
#pragma unroll
        for (int gg = 0; gg < 4; ++gg)
#pragma unroll
          for (int r = 0; r < 4; ++r)
            zs[((gg * 4 + uq) * 16 + ag * 4 + r) * 16 + lr] = acc[gg][r];
      }
      __syncthreads();                    // zs ready
      bf16_t* orow = h2s + (long long)(t + 1) * SLAB;
      bf16_t hv[4];
      if (kh == 0) {
#pragma unroll
        for (int r = 0; r < 4; ++r) {
          const int row = ag * 4 + r;
          const float zi = acc[0][r] + zs[((0 * 4 + uq) * 16 + row) * 16 + lr] + bias[0];
          const float zf = acc[1][r] + zs[((1 * 4 + uq) * 16 + row) * 16 + lr] + bias[1];
          const float zg = acc[2][r] + zs[((2 * 4 + uq) * 16 + row) * 16 + lr] + bias[2];
          const float zo = acc[3][r] + zs[((3 * 4 + uq) * 16 + row) * 16 + lr] + bias[3];
          const float ig = sigmoid_f(zi);
          const float fg = sigmoid_f(zf);
          const float gg = tanh_f(zg);
          const float og = sigmoid_f(zo);
          const float c  = fg * cst[r] + ig * gg;
          cst[r] = c;
          hv[r] = (bf16_t)(og * tanh_f(c));
          orow[(b0 + row) * HID + unit] = hv[r];          // plain (-> L2)
        }
      }
      waitcnt0();
      __syncthreads();                    // kh0 stores in L2 + zs consumed
      if (tid == 0) st_flag_sc0(fa2 + fidx(t + 1, g, hsl));
      if (kh == 0) {
#pragma unroll
        for (int r = 0; r < 4; ++r)       // fabric mirror
          st_bf16_sc01(orow + (b0 + ag * 4 + r) * HID + unit, hv[r]);
      }
    }
    waitcnt0();
    __syncthreads();
    if (tid == 0) st_flag_sc01(fb2 + fidx(T_STEPS, g, hsl));
  }
}

// ---------------------------------------------------------------- head
__global__ __launch_bounds__(64) void head_kernel(
    const bf16_t* __restrict__ h2,
    const float* __restrict__ Wd, const float* __restrict__ bd,
    const float* __restrict__ Ws, const float* __restrict__ bs,
    float* __restrict__ out)
{
  __shared__ float hsm[HID];
  __shared__ float hid[164];
  __shared__ float lg[8];
  const int b = blockIdx.x, tid = threadIdx.x;
  const bf16_t* hr = h2 + (long long)b * HID;
  for (int k = tid; k < HID; k += 64) hsm[k] = (float)hr[k];
  __syncthreads();
  for (int d = tid; d < 164; d += 64) {
    float a = bd[d];
    for (int k = 0; k < HID; ++k) a = fmaf(hsm[k], Wd[k * 164 + d], a);
    hid[d] = fmaxf(a, 0.f);
  }
  __syncthreads();
  if (tid < 8) {
    float a = bs[tid];
    for (int k = 0; k < 164; ++k) a = fmaf(hid[k], Ws[k * 8 + tid], a);
    lg[tid] = a;
  }
  __syncthreads();
  if (tid < 8) {
    float m = lg[0];
#pragma unroll
    for (int j = 1; j < 8; ++j) m = fmaxf(m, lg[j]);
    float s = 0.f;
#pragma unroll
    for (int j = 0; j < 8; ++j) s += __expf(lg[j] - m);
    out[b * 8 + tid] = __expf(lg[tid] - m) / s;
  }
}

// ---------------------------------------------------------------- launch
extern "C" void kernel_launch(void* const* d_in, const int* in_sizes, int n_in,
                              void* d_out, int out_size, void* d_ws, size_t ws_size,
                              hipStream_t stream)
{
  const float* x  = (const float*)d_in[0];
  const float* W1 = (const float*)d_in[1];
  const float* U1 = (const float*)d_in[2];
  const float* b1 = (const float*)d_in[3];
  const float* W2 = (const float*)d_in[4];
  const float* U2 = (const float*)d_in[5];
  const float* b2 = (const float*)d_in[6];
  const float* Wd = (const float*)d_in[7];
  const float* bd = (const float*)d_in[8];
  const float* Ws = (const float*)d_in[9];
  const float* bs = (const float*)d_in[10];
  (void)in_sizes; (void)n_in; (void)out_size; (void)ws_size;

  char* p = (char*)d_ws;
  size_t off = 0;
  auto carve = [&](size_t bytes) -> void* {
    void* r = p + off;
    off = (off + bytes + 255) & ~(size_t)255;
    return r;
  };
  bf16_t* xT  = (bf16_t*)carve((size_t)XT_ELEMS * 2);
  bf16_t* seq = (bf16_t*)carve((size_t)(T_STEPS + 1) * SLAB * 2);
  bf16_t* h2s = (bf16_t*)carve((size_t)(T_STEPS + 1) * SLAB * 2);
  unsigned int* fa1 = (unsigned int*)carve((size_t)F1N * 4);
  unsigned int* fb1 = (unsigned int*)carve((size_t)F1N * 4);
  unsigned int* fa2 = (unsigned int*)carve((size_t)F2N * 4);
  unsigned int* fb2 = (unsigned int*)carve((size_t)F2N * 4);

  const long long prep_total = (long long)XT_ELEMS + SLAB + SLAB + 2*F1N + 2*F2N;
  const int pb = (int)((prep_total + 255) / 256);

  prep_kernel<<<pb, 256, 0, stream>>>(x, xT, seq, h2s, fa1, fb1, fa2, fb2);
  lstm_fused<<<96, 512, 0, stream>>>(W1, U1, b1, W2, U2, b2,
                                     xT, seq, h2s, fa1, fb1, fa2, fb2);
  head_kernel<<<B_REAL, 64, 0, stream>>>(h2s + (long long)T_STEPS * SLAB,
                                         Wd, bd, Ws, bs, (float*)d_out);
}